// Round 6
// baseline (10292.000 us; speedup 1.0000x reference)
//
#include <hip/hip_runtime.h>
#include <stdint.h>

// 2-layer bidirectional LSTM, T=512 B=64 D=512 H=512.
// Per layer: 2 dirs x 64 WGs x 4 waves; per-WG 32 gate cols; Wi in LDS,
// Wh PINNED in VGPRs; tag-in-data h exchange (sc0 sc1) through LLC.
// Step pipeline: A(t+1) prefetched into regs (counted vmcnt(5) at loop top),
// sentinel issued before x-GEMM, h-GEMM runs pure-register after the wait.

#define TT 512
#define BATCH 64
#define HH 512
#define NWG 64
#define NCOLS 32

typedef __attribute__((ext_vector_type(8))) short vshort8;
typedef __attribute__((ext_vector_type(4))) float vfloat4;
typedef __attribute__((ext_vector_type(4))) unsigned int vuint4;

__device__ __forceinline__ vfloat4 mfma16(vshort8 a, vshort8 b, vfloat4 c) {
    return __builtin_amdgcn_mfma_f32_16x16x32_bf16(a, b, c, 0, 0, 0);
}

__device__ __forceinline__ float sigmoidf_(float x) {
    return 1.f / (1.f + __expf(-x));
}
__device__ __forceinline__ float tanhf_(float x) {
    float e = __expf(2.f * x);
    return 1.f - 2.f / (e + 1.f);
}
__device__ __forceinline__ unsigned short f2bf(float f) {
    uint32_t u = __float_as_uint(f);
    uint32_t r = (u + 0x7fffu + ((u >> 16) & 1u)) >> 16;
    return (unsigned short)r;
}

__global__ void cvt_f32_bf16(const float* __restrict__ src,
                             unsigned short* __restrict__ dst, int n) {
    int i = (blockIdx.x * blockDim.x + threadIdx.x) * 4;
    if (i + 3 < n) {
        float4 v = *(const float4*)(src + i);
        uint2 p;
        p.x = (uint32_t)f2bf(v.x) | ((uint32_t)f2bf(v.y) << 16);
        p.y = (uint32_t)f2bf(v.z) | ((uint32_t)f2bf(v.w) << 16);
        *(uint2*)(dst + i) = p;
    }
}

// DIN: input feature size of this layer (512 or 1024).
// WRITE_BF16: phase A writes bf16 o0; else writes fp32 o1 to d_out.
template <int DIN, bool WRITE_BF16>
__launch_bounds__(256, 1)
__global__ void lstm_phase(const unsigned short* __restrict__ A,   // [T][B][DIN] bf16
                           const unsigned short* __restrict__ Wi,  // [2][4H][DIN] bf16
                           const float* __restrict__ Whf,          // [2][4H][H] f32
                           const float* __restrict__ bias,         // [2][4H] f32
                           uint32_t* __restrict__ hbuf32,          // [4][B][H] u32 {h|tag}
                           unsigned short* __restrict__ obf,       // [T][B][2H] bf16 (A)
                           float* __restrict__ of32,               // [T][B][2H] f32 (B)
                           float* __restrict__ hn,                 // [2][B][H] f32
                           float* __restrict__ cn)                 // [2][B][H] f32
{
    __shared__ unsigned short Wlds[NCOLS * DIN];  // Wi slice only, 32KB or 64KB

    const int tid = threadIdx.x;
    const int dir = blockIdx.x >> 6;
    const int wg = blockIdx.x & 63;
    const int j0 = wg * 8;
    const int lane = tid & 63;
    const int wave = tid >> 6;

    // ---- stage Wi slice into LDS (swizzled: byte ^= (n&7)<<4) ----
    for (int chunk = tid; chunk < NCOLS * DIN / 8; chunk += 256) {
        int n = chunk / (DIN / 8);
        int k8 = (chunk % (DIN / 8)) * 8;
        int grow = (n >> 3) * HH + j0 + (n & 7);
        vshort8 v = *(const vshort8*)(Wi + ((size_t)dir * 4 * HH + grow) * DIN + k8);
        int byte = n * DIN * 2 + ((k8 * 2) ^ ((n & 7) << 4));
        *(vshort8*)((char*)Wlds + byte) = v;
    }
    __syncthreads();

    // ---- per-lane constants ----
    const int arow = wave * 16 + (lane & 15);
    const int kOff = (lane >> 4) * 8;     // k offset in elements / u32 cols
    const int klane = (lane >> 4) * 16;   // k offset in bytes (bf16)
    const int n0 = lane & 15;
    const int swz = (n0 & 7) << 4;
    const int nb0 = n0 * DIN * 2;
    const int nb1 = (16 + n0) * DIN * 2;
    const int grow0 = (n0 >> 3) * HH + j0 + (n0 & 7);
    const int grow1 = ((n0 >> 3) + 2) * HH + j0 + (n0 & 7);
    const float bias0 = bias[dir * 4 * HH + grow0];
    const float bias1 = bias[dir * 4 * HH + grow1];
    const bool lo = (lane & 8) == 0;
    const int jcol = j0 + (lane & 7);
    const int hrowb = wave * 16 + ((lane >> 4) << 2);
    const int scol = (lane & 15) * 32 + (lane >> 4) * 8;  // sentinel col (1 per WG)

    // ---- Wh -> PINNED registers: f32 load, cvt to bf16, asm pin ----
    const float* whf0 = Whf + ((size_t)dir * 4 * HH + grow0) * HH + kOff;
    const float* whf1 = Whf + ((size_t)dir * 4 * HH + grow1) * HH + kOff;
    vshort8 wh0r[16], wh1r[16];
#pragma unroll
    for (int kk = 0; kk < 16; ++kk) {
        float4 a0 = *(const float4*)(whf0 + kk * 32);
        float4 a1 = *(const float4*)(whf0 + kk * 32 + 4);
        float4 b0 = *(const float4*)(whf1 + kk * 32);
        float4 b1 = *(const float4*)(whf1 + kk * 32 + 4);
        vshort8 a, b;
        a[0] = (short)f2bf(a0.x); a[1] = (short)f2bf(a0.y);
        a[2] = (short)f2bf(a0.z); a[3] = (short)f2bf(a0.w);
        a[4] = (short)f2bf(a1.x); a[5] = (short)f2bf(a1.y);
        a[6] = (short)f2bf(a1.z); a[7] = (short)f2bf(a1.w);
        b[0] = (short)f2bf(b0.x); b[1] = (short)f2bf(b0.y);
        b[2] = (short)f2bf(b0.z); b[3] = (short)f2bf(b0.w);
        b[4] = (short)f2bf(b1.x); b[5] = (short)f2bf(b1.y);
        b[6] = (short)f2bf(b1.z); b[7] = (short)f2bf(b1.w);
        wh0r[kk] = a;
        wh1r[kk] = b;
        asm volatile("" : "+v"(wh0r[kk]), "+v"(wh1r[kk]));
    }

    float cstate[4] = {0.f, 0.f, 0.f, 0.f};

    // ---- prologue A(t0) prefetch: 16 loads, oldest in the VMEM FIFO ----
    vshort8 pre[16];
    {
        const int t0 = dir ? (TT - 1) : 0;
        const unsigned short* ap0 = A + ((size_t)t0 * BATCH + arow) * DIN + kOff;
#pragma unroll
        for (int kk = 0; kk < 16; ++kk)
            asm volatile("global_load_dwordx4 %0, %1, off"
                         : "=v"(pre[kk]) : "v"(ap0 + kk * 32));
    }

    for (int s = 0; s < TT; ++s) {
        const int t = dir ? (TT - 1 - s) : s;
        const uint32_t want = (uint32_t)s;
        const uint32_t* rowbase =
            hbuf32 + (((dir << 1) | ((s - 1) & 1)) * BATCH + arow) * HH;

        vfloat4 acc0, acc1;
        acc0[0] = acc0[1] = acc0[2] = acc0[3] = bias0;
        acc1[0] = acc1[1] = acc1[2] = acc1[3] = bias1;

        // ---- loop-top wait: sentinel issued early, counted vmcnt ----
        uint32_t sent;
        if (s > 0) {
            asm volatile("global_load_dword %0, %1, off sc0 sc1"
                         : "=v"(sent) : "v"(rowbase + scol));
            // FIFO: [pre x16][h-store x2][out-store x2][sent] -> wait pre only
            asm volatile("s_waitcnt vmcnt(5)" ::: "memory");
        } else {
            asm volatile("s_waitcnt vmcnt(0)" ::: "memory");
        }
        __builtin_amdgcn_sched_barrier(0);

        // ---- x-GEMM from prefetched regs + Wi LDS ----
        const unsigned short* ap = A + ((size_t)t * BATCH + arow) * DIN + kOff;
#pragma unroll
        for (int kk = 0; kk < DIN / 32; ++kk) {
            vshort8 a = (kk < 16) ? pre[kk] : *(const vshort8*)(ap + kk * 32);
            int kb = kk * 64 + klane;
            vshort8 b0 = *(const vshort8*)((const char*)Wlds + nb0 + (kb ^ swz));
            vshort8 b1 = *(const vshort8*)((const char*)Wlds + nb1 + (kb ^ swz));
            acc0 = mfma16(a, b0, acc0);
            acc1 = mfma16(a, b1, acc1);
        }

        // ---- h exchange: sentinel poll, batched load + packed-tag verify ----
        vuint4 hd[32];
        if (s > 0) {
            for (;;) {
                asm volatile("s_waitcnt vmcnt(0)" ::: "memory");
                __builtin_amdgcn_sched_barrier(0);
                if (!__any(((sent ^ want) & 0xffffu) != 0)) break;
                asm volatile("global_load_dword %0, %1, off sc0 sc1"
                             : "=v"(sent) : "v"(rowbase + scol));
            }
            const uint32_t* rbase = rowbase + kOff;
            const uint32_t want2 = want | (want << 16);
            for (;;) {
#pragma unroll
                for (int q = 0; q < 32; ++q)
                    asm volatile("global_load_dwordx4 %0, %1, off sc0 sc1"
                                 : "=v"(hd[q])
                                 : "v"(rbase + (q >> 1) * 32 + (q & 1) * 4));
                asm volatile("s_waitcnt vmcnt(0)" ::: "memory");
                __builtin_amdgcn_sched_barrier(0);
                uint32_t diff = 0;
#pragma unroll
                for (int q = 0; q < 32; ++q) {
                    uint32_t t01 = __builtin_amdgcn_perm(hd[q][1], hd[q][0], 0x05040100u);
                    uint32_t t23 = __builtin_amdgcn_perm(hd[q][3], hd[q][2], 0x05040100u);
                    diff |= (t01 ^ want2) | (t23 ^ want2);
                }
                if (!__any(diff != 0)) break;
                __builtin_amdgcn_s_sleep(1);
            }
            __builtin_amdgcn_sched_barrier(0);
        }

        // ---- A(t+1) prefetch: issue now, flight hides under h-GEMM+epilogue ----
        if (s < TT - 1) {
            const int tn = dir ? (TT - 2 - s) : (s + 1);
            const unsigned short* apn = A + ((size_t)tn * BATCH + arow) * DIN + kOff;
#pragma unroll
            for (int kk = 0; kk < 16; ++kk)
                asm volatile("global_load_dwordx4 %0, %1, off"
                             : "=v"(pre[kk]) : "v"(apn + kk * 32));
        }

        // ---- h-GEMM: repack {tag|h} -> bf16x8, MFMA vs pinned Wh regs ----
        if (s > 0) {
#pragma unroll
            for (int kk = 0; kk < 16; ++kk) {
                uint32_t d0 = __builtin_amdgcn_perm(hd[2 * kk][1], hd[2 * kk][0], 0x07060302u);
                uint32_t d1 = __builtin_amdgcn_perm(hd[2 * kk][3], hd[2 * kk][2], 0x07060302u);
                uint32_t d2 = __builtin_amdgcn_perm(hd[2 * kk + 1][1], hd[2 * kk + 1][0], 0x07060302u);
                uint32_t d3 = __builtin_amdgcn_perm(hd[2 * kk + 1][3], hd[2 * kk + 1][2], 0x07060302u);
                vuint4 tt = {d0, d1, d2, d3};
                vshort8 ha = __builtin_bit_cast(vshort8, tt);
                acc0 = mfma16(ha, wh0r[kk], acc0);
                acc1 = mfma16(ha, wh1r[kk], acc1);
            }
        }

        // ---- epilogue: exchange i/f and g/o halves, LSTM cell update ----
        float hval[4];
#pragma unroll
        for (int r = 0; r < 4; ++r) {
            float own0 = acc0[r], own1 = acc1[r];
            float oth0 = __shfl_xor(own0, 8, 64);
            float oth1 = __shfl_xor(own1, 8, 64);
            float iv = lo ? own0 : oth0;
            float fv = lo ? oth0 : own0;
            float gv = lo ? own1 : oth1;
            float ov = lo ? oth1 : own1;
            float cnew = sigmoidf_(fv) * cstate[r] + sigmoidf_(iv) * tanhf_(gv);
            cstate[r] = cnew;
            hval[r] = sigmoidf_(ov) * tanhf_(cnew);
        }

        // ---- stores: tagged h (sc0 sc1) first, then layer output (asm) ----
        uint32_t* hw = hbuf32 + (size_t)(((dir << 1) | (s & 1)) * BATCH) * HH;
        const int rA = lo ? 0 : 2;
        const uint32_t tagv = (uint32_t)(s + 1);
        unsigned short hb[2];
        hb[0] = f2bf(hval[rA]);
        hb[1] = f2bf(hval[rA + 1]);
#pragma unroll
        for (int q = 0; q < 2; ++q) {
            int row = hrowb + rA + q;
            uint32_t val = ((uint32_t)hb[q] << 16) | tagv;
            uint32_t* wp = hw + row * HH + jcol;
            asm volatile("global_store_dword %0, %1, off sc0 sc1"
                         :: "v"(wp), "v"(val) : "memory");
        }
#pragma unroll
        for (int q = 0; q < 2; ++q) {
            int row = hrowb + rA + q;
            if constexpr (WRITE_BF16) {
                unsigned short* op =
                    obf + ((size_t)t * BATCH + row) * (2 * HH) + dir * HH + jcol;
                uint32_t v32 = hb[q];
                asm volatile("global_store_short %0, %1, off"
                             :: "v"(op), "v"(v32) : "memory");
            } else {
                float* op = of32 + ((size_t)t * BATCH + row) * (2 * HH) + dir * HH + jcol;
                asm volatile("global_store_dword %0, %1, off"
                             :: "v"(op), "v"(hval[rA + q]) : "memory");
            }
        }
        if (s == TT - 1) {
#pragma unroll
            for (int q = 0; q < 2; ++q) {
                int r = rA + q, row = hrowb + r;
                hn[(dir * BATCH + row) * HH + jcol] = hval[r];
                cn[(dir * BATCH + row) * HH + jcol] = cstate[r];
            }
        }
    }
}

extern "C" void kernel_launch(void* const* d_in, const int* in_sizes, int n_in,
                              void* d_out, int out_size, void* d_ws, size_t ws_size,
                              hipStream_t stream) {
    const float* x = (const float*)d_in[0];
    const float* Wi0 = (const float*)d_in[1];
    const float* Wh0 = (const float*)d_in[2];
    const float* b0 = (const float*)d_in[3];
    const float* Wi1 = (const float*)d_in[4];
    const float* Wh1 = (const float*)d_in[5];
    const float* b1 = (const float*)d_in[6];

    char* ws = (char*)d_ws;
    // ws layout (bytes); total ~111MB
    uint32_t* hbufA = (uint32_t*)(ws);                        // 512KB
    uint32_t* hbufB = (uint32_t*)(ws + 524288);               // 512KB
    unsigned short* wi0b = (unsigned short*)(ws + 1048576);   // 4MB
    unsigned short* wi1b = (unsigned short*)(ws + 5242880);   // 8MB
    unsigned short* xb = (unsigned short*)(ws + 13631488);    // 32MB
    unsigned short* o0 = (unsigned short*)(ws + 47185920);    // 64MB

    float* out = (float*)d_out;
    const size_t O1SZ = (size_t)TT * BATCH * 2 * HH;
    float* hn_base = out + O1SZ;
    float* cn_base = out + O1SZ + 4 * BATCH * HH;

    // clear both tag buffers (kills poison / previous-replay tags)
    hipMemsetAsync(hbufA, 0, 1048576, stream);

    // fp32 -> bf16 conversions
    {
        int n;
        n = TT * BATCH * 512;
        cvt_f32_bf16<<<n / 1024, 256, 0, stream>>>(x, xb, n);
        n = 2 * 2048 * 512;
        cvt_f32_bf16<<<n / 1024, 256, 0, stream>>>(Wi0, wi0b, n);
        n = 2 * 2048 * 1024;
        cvt_f32_bf16<<<n / 1024, 256, 0, stream>>>(Wi1, wi1b, n);
    }

    // phase A: layer 0
    lstm_phase<512, true><<<128, 256, 0, stream>>>(
        xb, wi0b, Wh0, b0, hbufA, o0, nullptr, hn_base, cn_base);

    // phase B: layer 1
    lstm_phase<1024, false><<<128, 256, 0, stream>>>(
        o0, wi1b, Wh1, b1, hbufB, nullptr, out,
        hn_base + 2 * BATCH * HH, cn_base + 2 * BATCH * HH);
}

// Round 7
// 8413.979 us; speedup vs baseline: 1.2232x; 1.2232x over previous
//
#include <hip/hip_runtime.h>
#include <stdint.h>

// 2-layer bidirectional LSTM, T=512 B=64 D=512 H=512.
// Per layer: 2 dirs x 64 WGs x 4 waves; per-WG 32 gate cols; Wi+Wh in LDS.
// h exchange: write-once 32-step ring of tagged u32 {h_bf16|tag16} stored
// sc0 sc1 (through to LLC); producer drains + atomicAdd to per-(dir,wave)
// counter; consumer polls ONE uniform counter line, then bulk-loads the ring
// slot with NORMAL CACHED loads (same-XCD WGs share one LLC fill via L2).
// Tags catch rare stale-L2 lines (ring reuse / memset residue) -> sc0sc1 retry.

#define TT 512
#define BATCH 64
#define HH 512
#define NCOLS 32
#define RING 32

typedef __attribute__((ext_vector_type(8))) short vshort8;
typedef __attribute__((ext_vector_type(4))) float vfloat4;
typedef __attribute__((ext_vector_type(4))) unsigned int vuint4;

__device__ __forceinline__ vfloat4 mfma16(vshort8 a, vshort8 b, vfloat4 c) {
    return __builtin_amdgcn_mfma_f32_16x16x32_bf16(a, b, c, 0, 0, 0);
}

__device__ __forceinline__ float sigmoidf_(float x) {
    return 1.f / (1.f + __expf(-x));
}
__device__ __forceinline__ float tanhf_(float x) {
    float e = __expf(2.f * x);
    return 1.f - 2.f / (e + 1.f);
}
__device__ __forceinline__ unsigned short f2bf(float f) {
    uint32_t u = __float_as_uint(f);
    uint32_t r = (u + 0x7fffu + ((u >> 16) & 1u)) >> 16;
    return (unsigned short)r;
}

__global__ void cvt_f32_bf16(const float* __restrict__ src,
                             unsigned short* __restrict__ dst, int n) {
    int i = (blockIdx.x * blockDim.x + threadIdx.x) * 4;
    if (i + 3 < n) {
        float4 v = *(const float4*)(src + i);
        uint2 p;
        p.x = (uint32_t)f2bf(v.x) | ((uint32_t)f2bf(v.y) << 16);
        p.y = (uint32_t)f2bf(v.z) | ((uint32_t)f2bf(v.w) << 16);
        *(uint2*)(dst + i) = p;
    }
}

// DIN: input feature size of this layer (512 or 1024).
// WRITE_BF16: phase A writes bf16 o0; else writes fp32 o1 to d_out.
template <int DIN, bool WRITE_BF16>
__launch_bounds__(256, 1)
__global__ void lstm_phase(const unsigned short* __restrict__ A,   // [T][B][DIN] bf16
                           const unsigned short* __restrict__ Wi,  // [2][4H][DIN] bf16
                           const float* __restrict__ Whf,          // [2][4H][H] f32
                           const float* __restrict__ bias,         // [2][4H] f32
                           uint32_t* __restrict__ ring,            // [2][RING][B][H] u32
                           uint32_t* __restrict__ cnt,             // [2][4] x 128B-strided
                           unsigned short* __restrict__ obf,       // [T][B][2H] bf16 (A)
                           float* __restrict__ of32,               // [T][B][2H] f32 (B)
                           float* __restrict__ hn,                 // [2][B][H] f32
                           float* __restrict__ cn)                 // [2][B][H] f32
{
    __shared__ unsigned short Wlds[NCOLS * DIN];  // Wi slice, 32KB or 64KB
    __shared__ unsigned short Whlds[NCOLS * HH];  // Wh slice, 32KB

    const int tid = threadIdx.x;
    const int dir = blockIdx.x >> 6;
    const int wg = blockIdx.x & 63;
    const int j0 = wg * 8;
    const int lane = tid & 63;
    const int wave = tid >> 6;

    // ---- stage Wi slice into LDS (swizzled: byte ^= (n&7)<<4) ----
    for (int chunk = tid; chunk < NCOLS * DIN / 8; chunk += 256) {
        int n = chunk / (DIN / 8);
        int k8 = (chunk % (DIN / 8)) * 8;
        int grow = (n >> 3) * HH + j0 + (n & 7);
        vshort8 v = *(const vshort8*)(Wi + ((size_t)dir * 4 * HH + grow) * DIN + k8);
        int byte = n * DIN * 2 + ((k8 * 2) ^ ((n & 7) << 4));
        *(vshort8*)((char*)Wlds + byte) = v;
    }
    // ---- stage Wh slice into LDS with f32->bf16 cvt (same swizzle) ----
    for (int chunk = tid; chunk < NCOLS * HH / 8; chunk += 256) {
        int n = chunk / (HH / 8);
        int k8 = (chunk % (HH / 8)) * 8;
        int grow = (n >> 3) * HH + j0 + (n & 7);
        const float* src = Whf + ((size_t)dir * 4 * HH + grow) * HH + k8;
        float4 f0 = *(const float4*)(src);
        float4 f1 = *(const float4*)(src + 4);
        vshort8 v;
        v[0] = (short)f2bf(f0.x); v[1] = (short)f2bf(f0.y);
        v[2] = (short)f2bf(f0.z); v[3] = (short)f2bf(f0.w);
        v[4] = (short)f2bf(f1.x); v[5] = (short)f2bf(f1.y);
        v[6] = (short)f2bf(f1.z); v[7] = (short)f2bf(f1.w);
        int byte = n * HH * 2 + ((k8 * 2) ^ ((n & 7) << 4));
        *(vshort8*)((char*)Whlds + byte) = v;
    }
    __syncthreads();

    // ---- per-lane constants ----
    const int arow = wave * 16 + (lane & 15);
    const int kOff = (lane >> 4) * 8;     // k offset in elements / u32 cols
    const int klane = (lane >> 4) * 16;   // k offset in bytes (bf16)
    const int n0 = lane & 15;
    const int swz = (n0 & 7) << 4;
    const int nb0 = n0 * DIN * 2;
    const int nb1 = (16 + n0) * DIN * 2;
    const int nb0h = n0 * HH * 2;
    const int nb1h = (16 + n0) * HH * 2;
    const int grow0 = (n0 >> 3) * HH + j0 + (n0 & 7);
    const int grow1 = ((n0 >> 3) + 2) * HH + j0 + (n0 & 7);
    const float bias0 = bias[dir * 4 * HH + grow0];
    const float bias1 = bias[dir * 4 * HH + grow1];
    const bool lo = (lane & 8) == 0;
    const int jcol = j0 + (lane & 7);
    const int hrowb = wave * 16 + ((lane >> 4) << 2);
    uint32_t* const cpoll = cnt + (dir * 4 + wave) * 32;  // own 128B line

    float cstate[4] = {0.f, 0.f, 0.f, 0.f};

    for (int s = 0; s < TT; ++s) {
        const int t = dir ? (TT - 1 - s) : s;

        vfloat4 acc0, acc1;
        acc0[0] = acc0[1] = acc0[2] = acc0[3] = bias0;
        acc1[0] = acc1[1] = acc1[2] = acc1[3] = bias1;

        // ---- x part: gates += x_t @ Wi^T (overlaps the coming wait) ----
        const unsigned short* ap = A + ((size_t)t * BATCH + arow) * DIN + kOff;
#pragma unroll 8
        for (int kk = 0; kk < DIN / 32; ++kk) {
            vshort8 a = *(const vshort8*)(ap + kk * 32);
            int kb = kk * 64 + klane;
            vshort8 b0 = *(const vshort8*)((const char*)Wlds + nb0 + (kb ^ swz));
            vshort8 b1 = *(const vshort8*)((const char*)Wlds + nb1 + (kb ^ swz));
            acc0 = mfma16(a, b0, acc0);
            acc1 = mfma16(a, b1, acc1);
        }

        // ---- h exchange ----
        if (s > 0) {
            // (1) poll aggregated counter: ONE uniform address per wave
            const uint32_t target = (uint32_t)(64 * s);
            for (;;) {
                uint32_t v;
                asm volatile(
                    "global_load_dword %0, %1, off sc0 sc1\n\t"
                    "s_waitcnt vmcnt(0)"
                    : "=v"(v) : "v"(cpoll) : "memory");
                if (__builtin_amdgcn_readfirstlane(v) >= target) break;
            }
            __builtin_amdgcn_sched_barrier(0);

            // (2) CACHED bulk load from ring slot (s-1)%RING
            const uint32_t* rbase =
                ring + (((size_t)(dir * RING + ((s - 1) & (RING - 1)))) * BATCH + arow) * HH +
                kOff;
            vuint4 hd[32];
#pragma unroll
            for (int q = 0; q < 32; ++q)
                hd[q] = *(const vuint4*)(rbase + (q >> 1) * 32 + (q & 1) * 4);

            // (3) verify tags (low16 == s); rare stale-L2 -> sc0sc1 retry
            const uint32_t want = (uint32_t)s;
            const uint32_t want2 = want | (want << 16);
            uint32_t diff = 0;
#pragma unroll
            for (int q = 0; q < 32; ++q) {
                uint32_t t01 = __builtin_amdgcn_perm(hd[q][1], hd[q][0], 0x05040100u);
                uint32_t t23 = __builtin_amdgcn_perm(hd[q][3], hd[q][2], 0x05040100u);
                diff |= (t01 ^ want2) | (t23 ^ want2);
            }
            if (__any(diff != 0)) {
                for (;;) {
#pragma unroll
                    for (int q = 0; q < 32; ++q)
                        asm volatile("global_load_dwordx4 %0, %1, off sc0 sc1"
                                     : "=v"(hd[q])
                                     : "v"(rbase + (q >> 1) * 32 + (q & 1) * 4));
                    asm volatile("s_waitcnt vmcnt(0)" ::: "memory");
                    __builtin_amdgcn_sched_barrier(0);
                    uint32_t d2 = 0;
#pragma unroll
                    for (int q = 0; q < 32; ++q) {
                        uint32_t t01 = __builtin_amdgcn_perm(hd[q][1], hd[q][0], 0x05040100u);
                        uint32_t t23 = __builtin_amdgcn_perm(hd[q][3], hd[q][2], 0x05040100u);
                        d2 |= (t01 ^ want2) | (t23 ^ want2);
                    }
                    if (!__any(d2 != 0)) break;
                    __builtin_amdgcn_s_sleep(1);
                }
            }

            // (4) repack {tag|h} -> bf16x8 fragments, h-GEMM from LDS Wh
#pragma unroll
            for (int kk = 0; kk < 16; ++kk) {
                uint32_t d0 = __builtin_amdgcn_perm(hd[2 * kk][1], hd[2 * kk][0], 0x07060302u);
                uint32_t d1 = __builtin_amdgcn_perm(hd[2 * kk][3], hd[2 * kk][2], 0x07060302u);
                uint32_t d2 = __builtin_amdgcn_perm(hd[2 * kk + 1][1], hd[2 * kk + 1][0], 0x07060302u);
                uint32_t d3 = __builtin_amdgcn_perm(hd[2 * kk + 1][3], hd[2 * kk + 1][2], 0x07060302u);
                vuint4 tt = {d0, d1, d2, d3};
                vshort8 ha = __builtin_bit_cast(vshort8, tt);
                int kb = kk * 64 + klane;
                vshort8 b0 = *(const vshort8*)((const char*)Whlds + nb0h + (kb ^ swz));
                vshort8 b1 = *(const vshort8*)((const char*)Whlds + nb1h + (kb ^ swz));
                acc0 = mfma16(ha, b0, acc0);
                acc1 = mfma16(ha, b1, acc1);
            }
        }

        // ---- epilogue: exchange i/f and g/o halves, LSTM cell update ----
        float hval[4];
#pragma unroll
        for (int r = 0; r < 4; ++r) {
            float own0 = acc0[r], own1 = acc1[r];
            float oth0 = __shfl_xor(own0, 8, 64);
            float oth1 = __shfl_xor(own1, 8, 64);
            float iv = lo ? own0 : oth0;
            float fv = lo ? oth0 : own0;
            float gv = lo ? own1 : oth1;
            float ov = lo ? oth1 : own1;
            float cnew = sigmoidf_(fv) * cstate[r] + sigmoidf_(iv) * tanhf_(gv);
            cstate[r] = cnew;
            hval[r] = sigmoidf_(ov) * tanhf_(cnew);
        }

        // ---- ring stores (tagged, sc0 sc1) + layer output stores ----
        uint32_t* hw = ring + ((size_t)(dir * RING + (s & (RING - 1))) * BATCH) * HH;
        const int rA = lo ? 0 : 2;
        const uint32_t tagv = (uint32_t)(s + 1);
#pragma unroll
        for (int q = 0; q < 2; ++q) {
            int r = rA + q, row = hrowb + r;
            unsigned short hb = f2bf(hval[r]);
            uint32_t val = ((uint32_t)hb << 16) | tagv;
            uint32_t* wp = hw + row * HH + jcol;
            asm volatile("global_store_dword %0, %1, off sc0 sc1"
                         :: "v"(wp), "v"(val) : "memory");
            if constexpr (WRITE_BF16)
                obf[((size_t)t * BATCH + row) * (2 * HH) + dir * HH + jcol] = hb;
            else
                of32[((size_t)t * BATCH + row) * (2 * HH) + dir * HH + jcol] = hval[r];
        }
        if (s == TT - 1) {
#pragma unroll
            for (int q = 0; q < 2; ++q) {
                int r = rA + q, row = hrowb + r;
                hn[(dir * BATCH + row) * HH + jcol] = hval[r];
                cn[(dir * BATCH + row) * HH + jcol] = cstate[r];
            }
        }

        // ---- release: drain ring stores -> post aggregated counter ----
        if (s < TT - 1) {
            asm volatile("s_waitcnt vmcnt(0)" ::: "memory");
            __builtin_amdgcn_sched_barrier(0);
            if (lane == 0) atomicAdd((unsigned int*)cpoll, 1u);
        }
    }
}

extern "C" void kernel_launch(void* const* d_in, const int* in_sizes, int n_in,
                              void* d_out, int out_size, void* d_ws, size_t ws_size,
                              hipStream_t stream) {
    const float* x = (const float*)d_in[0];
    const float* Wi0 = (const float*)d_in[1];
    const float* Wh0 = (const float*)d_in[2];
    const float* b0 = (const float*)d_in[3];
    const float* Wi1 = (const float*)d_in[4];
    const float* Wh1 = (const float*)d_in[5];
    const float* b1 = (const float*)d_in[6];

    char* ws = (char*)d_ws;
    // ws layout (bytes); total ~116 MB (matches R1's proven footprint)
    uint32_t* cntA = (uint32_t*)(ws);                          // 2KB
    uint32_t* cntB = (uint32_t*)(ws + 2048);                   // 2KB
    uint32_t* ringA = (uint32_t*)(ws + 8192);                  // 8MB
    unsigned short* wi0b = (unsigned short*)(ws + 8396800);    // 4MB
    unsigned short* wi1b = (unsigned short*)(ws + 12591104);   // 8MB
    unsigned short* xb = (unsigned short*)(ws + 20979712);     // 32MB
    uint32_t* ringB = (uint32_t*)(ws + 20979712);              // overlays dead xb
    unsigned short* o0 = (unsigned short*)(ws + 54534144);     // 64MB -> 116.0MB

    float* out = (float*)d_out;
    const size_t O1SZ = (size_t)TT * BATCH * 2 * HH;
    float* hn_base = out + O1SZ;
    float* cn_base = out + O1SZ + 4 * BATCH * HH;

    // clear counters + phase-A ring (kills poison / previous-replay tags)
    hipMemsetAsync(ws, 0, 4096, stream);
    hipMemsetAsync(ringA, 0, 8388608, stream);

    // fp32 -> bf16 conversions
    {
        int n;
        n = TT * BATCH * 512;
        cvt_f32_bf16<<<n / 1024, 256, 0, stream>>>(x, xb, n);
        n = 2 * 2048 * 512;
        cvt_f32_bf16<<<n / 1024, 256, 0, stream>>>(Wi0, wi0b, n);
        n = 2 * 2048 * 1024;
        cvt_f32_bf16<<<n / 1024, 256, 0, stream>>>(Wi1, wi1b, n);
    }

    // phase A: layer 0
    lstm_phase<512, true><<<128, 256, 0, stream>>>(
        xb, wi0b, Wh0, b0, ringA, cntA, o0, nullptr, hn_base, cn_base);

    // clear phase-B ring (xb is dead after phase A)
    hipMemsetAsync(ringB, 0, 8388608, stream);

    // phase B: layer 1
    lstm_phase<1024, false><<<128, 256, 0, stream>>>(
        o0, wi1b, Wh1, b1, ringB, cntB, nullptr, out,
        hn_base + 2 * BATCH * HH, cn_base + 2 * BATCH * HH);
}

// Round 9
// 8260.504 us; speedup vs baseline: 1.2459x; 1.0186x over previous
//
#include <hip/hip_runtime.h>
#include <stdint.h>

// 2-layer bidirectional LSTM, T=512 B=64 D=512 H=512.
// R5 structure (tag-in-data h exchange through LLC, Wi+Wh in LDS, sentinel
// poll + batched verify) + DVFS-pinning BURNER workgroups: grid 256, blocks
// 0-127 do the LSTM, blocks 128-255 spin on VALU FMA chains until the done
// counter says all workers finished. Burners write nothing (deterministic);
// they exist to hold the clock governor at high frequency while the workers
// sit in latency-bound sync waits (~90% idle -> suspected deep downclock).

#define TT 512
#define BATCH 64
#define HH 512
#define NWG 64
#define NCOLS 32
#define NWORK 128

typedef __attribute__((ext_vector_type(8))) short vshort8;
typedef __attribute__((ext_vector_type(4))) float vfloat4;
typedef __attribute__((ext_vector_type(4))) unsigned int vuint4;

__device__ __forceinline__ vfloat4 mfma16(vshort8 a, vshort8 b, vfloat4 c) {
    return __builtin_amdgcn_mfma_f32_16x16x32_bf16(a, b, c, 0, 0, 0);
}

__device__ __forceinline__ float sigmoidf_(float x) {
    return 1.f / (1.f + __expf(-x));
}
__device__ __forceinline__ float tanhf_(float x) {
    float e = __expf(2.f * x);
    return 1.f - 2.f / (e + 1.f);
}
__device__ __forceinline__ unsigned short f2bf(float f) {
    uint32_t u = __float_as_uint(f);
    uint32_t r = (u + 0x7fffu + ((u >> 16) & 1u)) >> 16;
    return (unsigned short)r;
}

__global__ void cvt_f32_bf16(const float* __restrict__ src,
                             unsigned short* __restrict__ dst, int n) {
    int i = (blockIdx.x * blockDim.x + threadIdx.x) * 4;
    if (i + 3 < n) {
        float4 v = *(const float4*)(src + i);
        uint2 p;
        p.x = (uint32_t)f2bf(v.x) | ((uint32_t)f2bf(v.y) << 16);
        p.y = (uint32_t)f2bf(v.z) | ((uint32_t)f2bf(v.w) << 16);
        *(uint2*)(dst + i) = p;
    }
}

// DIN: input feature size of this layer (512 or 1024).
// WRITE_BF16: phase A writes bf16 o0; else writes fp32 o1 to d_out.
template <int DIN, bool WRITE_BF16>
__launch_bounds__(256, 1)
__global__ void lstm_phase(const unsigned short* __restrict__ A,   // [T][B][DIN] bf16
                           const unsigned short* __restrict__ Wi,  // [2][4H][DIN] bf16
                           const float* __restrict__ Whf,          // [2][4H][H] f32
                           const float* __restrict__ bias,         // [2][4H] f32
                           uint32_t* __restrict__ hbuf32,          // [4][B][H] u32 {h|tag}
                           int* __restrict__ done,                 // completion counter
                           unsigned short* __restrict__ obf,       // [T][B][2H] bf16 (A)
                           float* __restrict__ of32,               // [T][B][2H] f32 (B)
                           float* __restrict__ hn,                 // [2][B][H] f32
                           float* __restrict__ cn)                 // [2][B][H] f32
{
    // 64KB (max of both phases) + 32KB = 96KB -> exactly 1 WG/CU
    __shared__ unsigned short Wlds[NCOLS * 1024];  // Wi slice (DIN-strided)
    __shared__ unsigned short Whlds[NCOLS * HH];   // Wh slice, 32KB

    // ---- burner blocks: pin the clock, then exit ----
    if (blockIdx.x >= NWORK) {
        float z0 = 1.0f + (float)threadIdx.x * 1e-6f;
        float z1 = z0 + 0.25f, z2 = z0 + 0.5f, z3 = z0 + 0.75f;
        for (;;) {
            int v = __hip_atomic_load(done, __ATOMIC_RELAXED,
                                      __HIP_MEMORY_SCOPE_AGENT);
            if (v >= NWORK) break;
#pragma unroll 16
            for (int i = 0; i < 4096; ++i) {
                z0 = __builtin_fmaf(z0, 1.00000012f, 1.1920929e-7f);
                z1 = __builtin_fmaf(z1, 1.00000012f, 1.1920929e-7f);
                z2 = __builtin_fmaf(z2, 1.00000012f, 1.1920929e-7f);
                z3 = __builtin_fmaf(z3, 1.00000012f, 1.1920929e-7f);
            }
            asm volatile("" :: "v"(z0), "v"(z1), "v"(z2), "v"(z3));
        }
        return;
    }

    const int tid = threadIdx.x;
    const int dir = blockIdx.x >> 6;
    const int wg = blockIdx.x & 63;
    const int j0 = wg * 8;
    const int lane = tid & 63;
    const int wave = tid >> 6;

    // ---- stage Wi slice into LDS (swizzled: byte ^= (n&7)<<4) ----
    for (int chunk = tid; chunk < NCOLS * DIN / 8; chunk += 256) {
        int n = chunk / (DIN / 8);
        int k8 = (chunk % (DIN / 8)) * 8;
        int grow = (n >> 3) * HH + j0 + (n & 7);
        vshort8 v = *(const vshort8*)(Wi + ((size_t)dir * 4 * HH + grow) * DIN + k8);
        int byte = n * DIN * 2 + ((k8 * 2) ^ ((n & 7) << 4));
        *(vshort8*)((char*)Wlds + byte) = v;
    }
    // ---- stage Wh slice into LDS with f32->bf16 cvt (same swizzle) ----
    for (int chunk = tid; chunk < NCOLS * HH / 8; chunk += 256) {
        int n = chunk / (HH / 8);
        int k8 = (chunk % (HH / 8)) * 8;
        int grow = (n >> 3) * HH + j0 + (n & 7);
        const float* src = Whf + ((size_t)dir * 4 * HH + grow) * HH + k8;
        float4 f0 = *(const float4*)(src);
        float4 f1 = *(const float4*)(src + 4);
        vshort8 v;
        v[0] = (short)f2bf(f0.x); v[1] = (short)f2bf(f0.y);
        v[2] = (short)f2bf(f0.z); v[3] = (short)f2bf(f0.w);
        v[4] = (short)f2bf(f1.x); v[5] = (short)f2bf(f1.y);
        v[6] = (short)f2bf(f1.z); v[7] = (short)f2bf(f1.w);
        int byte = n * HH * 2 + ((k8 * 2) ^ ((n & 7) << 4));
        *(vshort8*)((char*)Whlds + byte) = v;
    }
    __syncthreads();

    // ---- per-lane constants ----
    const int arow = wave * 16 + (lane & 15);
    const int kOff = (lane >> 4) * 8;     // k offset in elements / u32 cols
    const int klane = (lane >> 4) * 16;   // k offset in bytes (bf16)
    const int n0 = lane & 15;
    const int swz = (n0 & 7) << 4;
    const int nb0 = n0 * DIN * 2;
    const int nb1 = (16 + n0) * DIN * 2;
    const int nb0h = n0 * HH * 2;
    const int nb1h = (16 + n0) * HH * 2;
    const int grow0 = (n0 >> 3) * HH + j0 + (n0 & 7);
    const int grow1 = ((n0 >> 3) + 2) * HH + j0 + (n0 & 7);
    const float bias0 = bias[dir * 4 * HH + grow0];
    const float bias1 = bias[dir * 4 * HH + grow1];
    const bool lo = (lane & 8) == 0;
    const int jcol = j0 + (lane & 7);
    const int hrowb = wave * 16 + ((lane >> 4) << 2);
    // sentinel column: one element from each producer WG's wave-stripe
    const int scol = (lane & 15) * 32 + (lane >> 4) * 8;

    float cstate[4] = {0.f, 0.f, 0.f, 0.f};

    for (int s = 0; s < TT; ++s) {
        const int t = dir ? (TT - 1 - s) : s;

        vfloat4 acc0, acc1;
        acc0[0] = acc0[1] = acc0[2] = acc0[3] = bias0;
        acc1[0] = acc1[1] = acc1[2] = acc1[3] = bias1;

        // ---- x part first (hidden under the h wait of the previous chain) ----
        const unsigned short* ap = A + ((size_t)t * BATCH + arow) * DIN + kOff;
#pragma unroll 8
        for (int kk = 0; kk < DIN / 32; ++kk) {
            vshort8 a = *(const vshort8*)(ap + kk * 32);
            int kb = kk * 64 + klane;
            vshort8 b0 = *(const vshort8*)((const char*)Wlds + nb0 + (kb ^ swz));
            vshort8 b1 = *(const vshort8*)((const char*)Wlds + nb1 + (kb ^ swz));
            acc0 = mfma16(a, b0, acc0);
            acc1 = mfma16(a, b1, acc1);
        }

        // ---- tagged h exchange ----
        if (s > 0) {
            const uint32_t* rowbase =
                hbuf32 + (((dir << 1) | ((s - 1) & 1)) * BATCH + arow) * HH;
            const uint32_t* rbase = rowbase + kOff;
            const uint32_t want = (uint32_t)s;

            // (1) cheap sentinel poll: 1 dword/lane, covers all 64 WGs
            for (;;) {
                uint32_t sent;
                asm volatile(
                    "global_load_dword %0, %1, off sc0 sc1\n\t"
                    "s_waitcnt vmcnt(0)"
                    : "=v"(sent) : "v"(rowbase + scol) : "memory");
                if (!__any(((sent ^ want) & 0xffffu) != 0)) break;
                __builtin_amdgcn_s_sleep(1);
            }

            // (2) full batched load + verify (normally 1 iteration)
            vuint4 hd[32];
            for (;;) {
#pragma unroll
                for (int q = 0; q < 32; ++q)
                    asm volatile("global_load_dwordx4 %0, %1, off sc0 sc1"
                                 : "=v"(hd[q])
                                 : "v"(rbase + (q >> 1) * 32 + (q & 1) * 4));
                asm volatile("s_waitcnt vmcnt(0)" ::: "memory");
                __builtin_amdgcn_sched_barrier(0);
                uint32_t diff = 0;
#pragma unroll
                for (int q = 0; q < 32; ++q)
                    diff |= (hd[q][0] ^ want) | (hd[q][1] ^ want) |
                            (hd[q][2] ^ want) | (hd[q][3] ^ want);
                if (!__any((diff & 0xffffu) != 0)) break;
                __builtin_amdgcn_s_sleep(1);
            }
            __builtin_amdgcn_sched_barrier(0);

            // (3) repack {tag|h} pairs -> bf16x8 fragments, h-GEMM from LDS Wh
#pragma unroll
            for (int kk = 0; kk < 16; ++kk) {
                uint32_t d0 = __builtin_amdgcn_perm(hd[2 * kk][1], hd[2 * kk][0], 0x07060302u);
                uint32_t d1 = __builtin_amdgcn_perm(hd[2 * kk][3], hd[2 * kk][2], 0x07060302u);
                uint32_t d2 = __builtin_amdgcn_perm(hd[2 * kk + 1][1], hd[2 * kk + 1][0], 0x07060302u);
                uint32_t d3 = __builtin_amdgcn_perm(hd[2 * kk + 1][3], hd[2 * kk + 1][2], 0x07060302u);
                vuint4 tt = {d0, d1, d2, d3};
                vshort8 ha = __builtin_bit_cast(vshort8, tt);
                int kb = kk * 64 + klane;
                vshort8 b0 = *(const vshort8*)((const char*)Whlds + nb0h + (kb ^ swz));
                vshort8 b1 = *(const vshort8*)((const char*)Whlds + nb1h + (kb ^ swz));
                acc0 = mfma16(ha, b0, acc0);
                acc1 = mfma16(ha, b1, acc1);
            }
        }

        // ---- epilogue: exchange i/f and g/o halves, LSTM cell update ----
        float hval[4];
#pragma unroll
        for (int r = 0; r < 4; ++r) {
            float own0 = acc0[r], own1 = acc1[r];
            float oth0 = __shfl_xor(own0, 8, 64);
            float oth1 = __shfl_xor(own1, 8, 64);
            float iv = lo ? own0 : oth0;
            float fv = lo ? oth0 : own0;
            float gv = lo ? own1 : oth1;
            float ov = lo ? oth1 : own1;
            float cnew = sigmoidf_(fv) * cstate[r] + sigmoidf_(iv) * tanhf_(gv);
            cstate[r] = cnew;
            hval[r] = sigmoidf_(ov) * tanhf_(cnew);
        }

        // ---- fire tagged h stores (no drain, no flag) + layer output ----
        uint32_t* hw = hbuf32 + (size_t)(((dir << 1) | (s & 1)) * BATCH) * HH;
        const int rA = lo ? 0 : 2;
        const uint32_t tagv = (uint32_t)(s + 1);
#pragma unroll
        for (int q = 0; q < 2; ++q) {
            int r = rA + q, row = hrowb + r;
            unsigned short hb = f2bf(hval[r]);
            uint32_t val = ((uint32_t)hb << 16) | tagv;
            uint32_t* wp = hw + row * HH + jcol;
            asm volatile("global_store_dword %0, %1, off sc0 sc1"
                         :: "v"(wp), "v"(val) : "memory");
            if constexpr (WRITE_BF16)
                obf[((size_t)t * BATCH + row) * (2 * HH) + dir * HH + jcol] = hb;
            else
                of32[((size_t)t * BATCH + row) * (2 * HH) + dir * HH + jcol] = hval[r];
        }
        if (s == TT - 1) {
#pragma unroll
            for (int q = 0; q < 2; ++q) {
                int r = rA + q, row = hrowb + r;
                hn[(dir * BATCH + row) * HH + jcol] = hval[r];
                cn[(dir * BATCH + row) * HH + jcol] = cstate[r];
            }
        }
    }

    // ---- signal completion (burners exit when all 128 workers are done) ----
    if (tid == 0) atomicAdd(done, 1);
}

extern "C" void kernel_launch(void* const* d_in, const int* in_sizes, int n_in,
                              void* d_out, int out_size, void* d_ws, size_t ws_size,
                              hipStream_t stream) {
    const float* x = (const float*)d_in[0];
    const float* Wi0 = (const float*)d_in[1];
    const float* Wh0 = (const float*)d_in[2];
    const float* b0 = (const float*)d_in[3];
    const float* Wi1 = (const float*)d_in[4];
    const float* Wh1 = (const float*)d_in[5];
    const float* b1 = (const float*)d_in[6];

    char* ws = (char*)d_ws;
    // ws layout (bytes); total ~114.3MB (R1 proved >=121.9MB available)
    uint32_t* hbufA = (uint32_t*)(ws);                        // 512KB
    uint32_t* hbufB = (uint32_t*)(ws + 524288);               // 512KB
    unsigned short* wi0b = (unsigned short*)(ws + 1048576);   // 4MB
    unsigned short* wi1b = (unsigned short*)(ws + 5242880);   // 8MB
    unsigned short* xb = (unsigned short*)(ws + 13631488);    // 32MB
    unsigned short* o0 = (unsigned short*)(ws + 47185920);    // 64MB -> ends 114294784
    int* doneA = (int*)(ws + 114294784);                      // 64B
    int* doneB = (int*)(ws + 114294848);                      // 64B

    float* out = (float*)d_out;
    const size_t O1SZ = (size_t)TT * BATCH * 2 * HH;
    float* hn_base = out + O1SZ;
    float* cn_base = out + O1SZ + 4 * BATCH * HH;

    // clear tag buffers + done counters (kills poison / previous-replay state)
    hipMemsetAsync(hbufA, 0, 1048576, stream);
    hipMemsetAsync(doneA, 0, 128, stream);

    // fp32 -> bf16 conversions
    {
        int n;
        n = TT * BATCH * 512;
        cvt_f32_bf16<<<n / 1024, 256, 0, stream>>>(x, xb, n);
        n = 2 * 2048 * 512;
        cvt_f32_bf16<<<n / 1024, 256, 0, stream>>>(Wi0, wi0b, n);
        n = 2 * 2048 * 1024;
        cvt_f32_bf16<<<n / 1024, 256, 0, stream>>>(Wi1, wi1b, n);
    }

    // phase A: layer 0 (128 workers + 128 burners)
    lstm_phase<512, true><<<256, 256, 0, stream>>>(
        xb, wi0b, Wh0, b0, hbufA, doneA, o0, nullptr, hn_base, cn_base);

    // phase B: layer 1
    lstm_phase<1024, false><<<256, 256, 0, stream>>>(
        o0, wi1b, Wh1, b1, hbufB, doneB, nullptr, out,
        hn_base + 2 * BATCH * HH, cn_base + 2 * BATCH * HH);
}

// Round 10
// 7379.578 us; speedup vs baseline: 1.3947x; 1.1194x over previous
//
#include <hip/hip_runtime.h>
#include <stdint.h>

// 2-layer bidirectional LSTM, T=512 B=64 D=512 H=512.
// Per layer: 2 dirs x 64 WGs x 4 waves; per-WG 32 gate cols; Wi in LDS,
// Wh PINNED in VGPRs. Minimum-request-rate exchange:
//   producer wave: 2 bf16 h-stores (sc0 sc1) -> per-wave vmcnt(0) drain ->
//                  lane0 atomicAdd(+1) to counter[dir][wave] (one 128B line)
//   consumer wave: poll ONE uniform counter line (readfirstlane + s_sleep),
//                  then bulk-load h ONCE (16 x dwordx4 sc0 sc1, no retry).
// Rationale: R2/R5/R9 all polled 64 LLC lines per wave per round (512 waves
// -> ~1e5 concurrent LLC requests, self-congesting); this cuts poll traffic
// 64x and removes the tag-verify retry path entirely.

#define TT 512
#define BATCH 64
#define HH 512
#define NWG 64
#define NCOLS 32

typedef __attribute__((ext_vector_type(8))) short vshort8;
typedef __attribute__((ext_vector_type(4))) float vfloat4;

__device__ __forceinline__ vfloat4 mfma16(vshort8 a, vshort8 b, vfloat4 c) {
    return __builtin_amdgcn_mfma_f32_16x16x32_bf16(a, b, c, 0, 0, 0);
}

__device__ __forceinline__ float sigmoidf_(float x) {
    return 1.f / (1.f + __expf(-x));
}
__device__ __forceinline__ float tanhf_(float x) {
    float e = __expf(2.f * x);
    return 1.f - 2.f / (e + 1.f);
}
__device__ __forceinline__ unsigned short f2bf(float f) {
    uint32_t u = __float_as_uint(f);
    uint32_t r = (u + 0x7fffu + ((u >> 16) & 1u)) >> 16;
    return (unsigned short)r;
}

__global__ void cvt_f32_bf16(const float* __restrict__ src,
                             unsigned short* __restrict__ dst, int n) {
    int i = (blockIdx.x * blockDim.x + threadIdx.x) * 4;
    if (i + 3 < n) {
        float4 v = *(const float4*)(src + i);
        uint2 p;
        p.x = (uint32_t)f2bf(v.x) | ((uint32_t)f2bf(v.y) << 16);
        p.y = (uint32_t)f2bf(v.z) | ((uint32_t)f2bf(v.w) << 16);
        *(uint2*)(dst + i) = p;
    }
}

// DIN: input feature size of this layer (512 or 1024).
// WRITE_BF16: phase A writes bf16 o0; else writes fp32 o1 to d_out.
template <int DIN, bool WRITE_BF16>
__launch_bounds__(256, 1)
__global__ void lstm_phase(const unsigned short* __restrict__ A,   // [T][B][DIN] bf16
                           const unsigned short* __restrict__ Wi,  // [2][4H][DIN] bf16
                           const float* __restrict__ Whf,          // [2][4H][H] f32
                           const float* __restrict__ bias,         // [2][4H] f32
                           unsigned short* __restrict__ hbuf,      // [2][2][B][H] bf16
                           uint32_t* __restrict__ cnt,             // [2][4] x 128B lines
                           unsigned short* __restrict__ obf,       // [T][B][2H] bf16 (A)
                           float* __restrict__ of32,               // [T][B][2H] f32 (B)
                           float* __restrict__ hn,                 // [2][B][H] f32
                           float* __restrict__ cn)                 // [2][B][H] f32
{
    __shared__ unsigned short Wlds[NCOLS * 1024];  // Wi slice (<=64KB used)
    __shared__ unsigned short Wpad[16 * 1024];     // pad to 96KB -> 1 WG/CU

    const int tid = threadIdx.x;
    // keep the pad alive (volatile store can't be elided)
    ((volatile unsigned short*)Wpad)[tid] = 0;

    const int dir = blockIdx.x >> 6;
    const int wg = blockIdx.x & 63;
    const int j0 = wg * 8;
    const int lane = tid & 63;
    const int wave = tid >> 6;

    // ---- stage Wi slice into LDS (swizzled: byte ^= (n&7)<<4) ----
    for (int chunk = tid; chunk < NCOLS * DIN / 8; chunk += 256) {
        int n = chunk / (DIN / 8);
        int k8 = (chunk % (DIN / 8)) * 8;
        int grow = (n >> 3) * HH + j0 + (n & 7);
        vshort8 v = *(const vshort8*)(Wi + ((size_t)dir * 4 * HH + grow) * DIN + k8);
        int byte = n * DIN * 2 + ((k8 * 2) ^ ((n & 7) << 4));
        *(vshort8*)((char*)Wlds + byte) = v;
    }
    __syncthreads();

    // ---- per-lane constants ----
    const int arow = wave * 16 + (lane & 15);
    const int kOff = (lane >> 4) * 8;     // k offset in elements
    const int klane = (lane >> 4) * 16;   // k offset in bytes (bf16)
    const int n0 = lane & 15;
    const int swz = (n0 & 7) << 4;
    const int nb0 = n0 * DIN * 2;
    const int nb1 = (16 + n0) * DIN * 2;
    const int grow0 = (n0 >> 3) * HH + j0 + (n0 & 7);
    const int grow1 = ((n0 >> 3) + 2) * HH + j0 + (n0 & 7);
    const float bias0 = bias[dir * 4 * HH + grow0];
    const float bias1 = bias[dir * 4 * HH + grow1];
    const bool lo = (lane & 8) == 0;
    const int jcol = j0 + (lane & 7);
    const int hrowb = wave * 16 + ((lane >> 4) << 2);
    uint32_t* const cline = cnt + (dir * 4 + wave) * 32;  // own 128B line

    // ---- Wh -> PINNED registers (f32 load, cvt, asm pin; R6-proven) ----
    const float* whf0 = Whf + ((size_t)dir * 4 * HH + grow0) * HH + kOff;
    const float* whf1 = Whf + ((size_t)dir * 4 * HH + grow1) * HH + kOff;
    vshort8 wh0r[16], wh1r[16];
#pragma unroll
    for (int kk = 0; kk < 16; ++kk) {
        float4 a0 = *(const float4*)(whf0 + kk * 32);
        float4 a1 = *(const float4*)(whf0 + kk * 32 + 4);
        float4 b0 = *(const float4*)(whf1 + kk * 32);
        float4 b1 = *(const float4*)(whf1 + kk * 32 + 4);
        vshort8 a, b;
        a[0] = (short)f2bf(a0.x); a[1] = (short)f2bf(a0.y);
        a[2] = (short)f2bf(a0.z); a[3] = (short)f2bf(a0.w);
        a[4] = (short)f2bf(a1.x); a[5] = (short)f2bf(a1.y);
        a[6] = (short)f2bf(a1.z); a[7] = (short)f2bf(a1.w);
        b[0] = (short)f2bf(b0.x); b[1] = (short)f2bf(b0.y);
        b[2] = (short)f2bf(b0.z); b[3] = (short)f2bf(b0.w);
        b[4] = (short)f2bf(b1.x); b[5] = (short)f2bf(b1.y);
        b[6] = (short)f2bf(b1.z); b[7] = (short)f2bf(b1.w);
        wh0r[kk] = a;
        wh1r[kk] = b;
        asm volatile("" : "+v"(wh0r[kk]), "+v"(wh1r[kk]));
    }

    float cstate[4] = {0.f, 0.f, 0.f, 0.f};

    for (int s = 0; s < TT; ++s) {
        const int t = dir ? (TT - 1 - s) : s;

        vfloat4 acc0, acc1;
        acc0[0] = acc0[1] = acc0[2] = acc0[3] = bias0;
        acc1[0] = acc1[1] = acc1[2] = acc1[3] = bias1;

        // ---- x part: gates += x_t @ Wi^T (off critical path: before wait) ----
        const unsigned short* ap = A + ((size_t)t * BATCH + arow) * DIN + kOff;
#pragma unroll 8
        for (int kk = 0; kk < DIN / 32; ++kk) {
            vshort8 a = *(const vshort8*)(ap + kk * 32);
            int kb = kk * 64 + klane;
            vshort8 b0 = *(const vshort8*)((const char*)Wlds + nb0 + (kb ^ swz));
            vshort8 b1 = *(const vshort8*)((const char*)Wlds + nb1 + (kb ^ swz));
            acc0 = mfma16(a, b0, acc0);
            acc1 = mfma16(a, b1, acc1);
        }

        // ---- h exchange: uniform counter poll, bulk load ONCE, h-GEMM ----
        if (s > 0) {
            const uint32_t target = 64u * (uint32_t)s;
            for (;;) {
                uint32_t v;
                asm volatile(
                    "global_load_dword %0, %1, off sc0 sc1\n\t"
                    "s_waitcnt vmcnt(0)"
                    : "=v"(v) : "v"(cline) : "memory");
                if (__builtin_amdgcn_readfirstlane(v) >= target) break;
                __builtin_amdgcn_s_sleep(1);
            }
            __builtin_amdgcn_sched_barrier(0);

            const unsigned short* hp =
                hbuf + (((dir << 1) | ((s - 1) & 1)) * BATCH + arow) * HH + kOff;
            vshort8 hd[16];
#pragma unroll
            for (int kk = 0; kk < 16; ++kk)
                asm volatile("global_load_dwordx4 %0, %1, off sc0 sc1"
                             : "=v"(hd[kk]) : "v"(hp + kk * 32));
            asm volatile("s_waitcnt vmcnt(0)" ::: "memory");
            __builtin_amdgcn_sched_barrier(0);
#pragma unroll
            for (int kk = 0; kk < 16; ++kk) {
                acc0 = mfma16(hd[kk], wh0r[kk], acc0);
                acc1 = mfma16(hd[kk], wh1r[kk], acc1);
            }
        }

        // ---- epilogue: exchange i/f and g/o halves, LSTM cell update ----
        float hval[4];
#pragma unroll
        for (int r = 0; r < 4; ++r) {
            float own0 = acc0[r], own1 = acc1[r];
            float oth0 = __shfl_xor(own0, 8, 64);
            float oth1 = __shfl_xor(own1, 8, 64);
            float iv = lo ? own0 : oth0;
            float fv = lo ? oth0 : own0;
            float gv = lo ? own1 : oth1;
            float ov = lo ? oth1 : own1;
            float cnew = sigmoidf_(fv) * cstate[r] + sigmoidf_(iv) * tanhf_(gv);
            cstate[r] = cnew;
            hval[r] = sigmoidf_(ov) * tanhf_(cnew);
        }

        // ---- h stores (sc0 sc1) -> per-wave drain -> counter post ----
        unsigned short* hw = hbuf + (size_t)(((dir << 1) | (s & 1)) * BATCH) * HH;
        const int rA = lo ? 0 : 2;
        unsigned short hb[2];
        hb[0] = f2bf(hval[rA]);
        hb[1] = f2bf(hval[rA + 1]);
#pragma unroll
        for (int q = 0; q < 2; ++q) {
            int row = hrowb + rA + q;
            unsigned short* wp = hw + row * HH + jcol;
            uint32_t v32 = hb[q];
            asm volatile("global_store_short %0, %1, off sc0 sc1"
                         :: "v"(wp), "v"(v32) : "memory");
        }
        asm volatile("s_waitcnt vmcnt(0)" ::: "memory");
        __builtin_amdgcn_sched_barrier(0);
        if (lane == 0) atomicAdd((unsigned int*)cline, 1u);

        // ---- layer output stores (off critical path, after the post) ----
#pragma unroll
        for (int q = 0; q < 2; ++q) {
            int row = hrowb + rA + q;
            if constexpr (WRITE_BF16)
                obf[((size_t)t * BATCH + row) * (2 * HH) + dir * HH + jcol] = hb[q];
            else
                of32[((size_t)t * BATCH + row) * (2 * HH) + dir * HH + jcol] =
                    hval[q == 0 ? rA : rA + 1];
        }
        if (s == TT - 1) {
#pragma unroll
            for (int q = 0; q < 2; ++q) {
                int r = rA + q, row = hrowb + r;
                hn[(dir * BATCH + row) * HH + jcol] = hval[r];
                cn[(dir * BATCH + row) * HH + jcol] = cstate[r];
            }
        }
    }
}

extern "C" void kernel_launch(void* const* d_in, const int* in_sizes, int n_in,
                              void* d_out, int out_size, void* d_ws, size_t ws_size,
                              hipStream_t stream) {
    const float* x = (const float*)d_in[0];
    const float* Wi0 = (const float*)d_in[1];
    const float* Wh0 = (const float*)d_in[2];
    const float* b0 = (const float*)d_in[3];
    const float* Wi1 = (const float*)d_in[4];
    const float* Wh1 = (const float*)d_in[5];
    const float* b1 = (const float*)d_in[6];

    char* ws = (char*)d_ws;
    // ws layout (bytes); total ~114.3MB (proven footprint)
    uint32_t* cntA = (uint32_t*)(ws);                          // 1KB
    uint32_t* cntB = (uint32_t*)(ws + 2048);                   // 1KB
    unsigned short* hbufA = (unsigned short*)(ws + 8192);      // 256KB
    unsigned short* hbufB = (unsigned short*)(ws + 270336);    // 256KB
    unsigned short* wi0b = (unsigned short*)(ws + 1048576);    // 4MB
    unsigned short* wi1b = (unsigned short*)(ws + 5242880);    // 8MB
    unsigned short* xb = (unsigned short*)(ws + 13631488);     // 32MB
    unsigned short* o0 = (unsigned short*)(ws + 47185920);     // 64MB

    float* out = (float*)d_out;
    const size_t O1SZ = (size_t)TT * BATCH * 2 * HH;
    float* hn_base = out + O1SZ;
    float* cn_base = out + O1SZ + 4 * BATCH * HH;

    // zero both phases' counters every call (replay-safe)
    hipMemsetAsync(ws, 0, 4096, stream);

    // fp32 -> bf16 conversions
    {
        int n;
        n = TT * BATCH * 512;
        cvt_f32_bf16<<<n / 1024, 256, 0, stream>>>(x, xb, n);
        n = 2 * 2048 * 512;
        cvt_f32_bf16<<<n / 1024, 256, 0, stream>>>(Wi0, wi0b, n);
        n = 2 * 2048 * 1024;
        cvt_f32_bf16<<<n / 1024, 256, 0, stream>>>(Wi1, wi1b, n);
    }

    // phase A: layer 0
    lstm_phase<512, true><<<128, 256, 0, stream>>>(
        xb, wi0b, Wh0, b0, hbufA, cntA, o0, nullptr, hn_base, cn_base);

    // phase B: layer 1
    lstm_phase<1024, false><<<128, 256, 0, stream>>>(
        o0, wi1b, Wh1, b1, hbufB, cntB, nullptr, out,
        hn_base + 2 * BATCH * HH, cn_base + 2 * BATCH * HH);
}